// Round 4
// baseline (183.692 us; speedup 1.0000x reference)
//
#include <hip/hip_runtime.h>
#include <math.h>

// PBC neighbor-list distances + per-cutoff masks, store-bandwidth-bound.
//
// Output layout (float32): [ d2[P] | mask0[P] | mask1[P] ... ]
//   P  = Pc + S*n*n,  Pc = n*(n-1)/2
//   p < Pc               : in-cell triu pair, row-major (i<j)
//   p = Pc + s*n*n+i*n+j : shifted-image pair (s,i,j)
// Masks written as float 0.0/1.0.
//
// Fast path (n%4==0, n<=2049, ncut<=4): grid (1, n, S+1).
//   z<S : shifted region. blockIdx.y=i, blockIdx.z=s are wave-uniform ->
//         shifts/cell/cutoffs/pos[i] become scalar loads; the f64 shift
//         matmul is computed once per wave, not per lane. Each thread owns
//         4 consecutive j (aligned float4 pos load + 3 nt vector stores).
//   z==S: triangular region, 4 elements/thread, per-element (i,j) decode.
// All store offsets fit in 32 bits (3P < 2^31 at this size).
//
// Distance math in f64 to match the numpy-f64 validator exactly at the
// mask boundary (d2 < cutoff^2); d2 itself has a loose (bf16-level)
// threshold. f64 cost is ~4 us; the kernel is store-bound.

typedef float f32x4 __attribute__((ext_vector_type(4)));  // native vec for nt-store

template <int NCUT>
__global__ void __launch_bounds__(256) nbr_fast(
    const float* __restrict__ pos,
    const float* __restrict__ cell,
    const float* __restrict__ shifts,
    const float* __restrict__ cutoffs,
    int n, int S,
    float* __restrict__ out, unsigned P, unsigned Pc)
{
    const int tid = threadIdx.x;
    const int s   = blockIdx.z;

    double cut2[NCUT];
#pragma unroll
    for (int c = 0; c < NCUT; ++c) {
        double cv = (double)cutoffs[c];
        cut2[c] = cv * cv;
    }

    if (s < S) {
        // ---------------- shifted-image region ----------------
        const unsigned j0 = (unsigned)tid << 2;
        if (j0 >= (unsigned)n) return;
        const unsigned i = blockIdx.y;

        // wave-uniform setup (scalar loads + once-per-wave f64)
        double s0 = (double)shifts[3*s+0], s1 = (double)shifts[3*s+1], s2 = (double)shifts[3*s+2];
        double sv0 = s0 * (double)cell[0] + s1 * (double)cell[3] + s2 * (double)cell[6];
        double sv1 = s0 * (double)cell[1] + s1 * (double)cell[4] + s2 * (double)cell[7];
        double sv2 = s0 * (double)cell[2] + s1 * (double)cell[5] + s2 * (double)cell[8];
        double pix = (double)pos[3*i+0];
        double piy = (double)pos[3*i+1];
        double piz = (double)pos[3*i+2];

        // 4 consecutive atoms j0..j0+3 = 12 floats, 16B-aligned (j0%4==0)
        const float4* pj = (const float4*)(pos + 3 * j0);
        float4 a = pj[0], b = pj[1], c4 = pj[2];
        float jx[4] = {a.x, a.w, b.z, c4.y};
        float jy[4] = {a.y, b.x, b.w, c4.z};
        float jz[4] = {a.z, b.y, c4.x, c4.w};

        f32x4 d2v;
        f32x4 mv[NCUT];
#pragma unroll
        for (int k = 0; k < 4; ++k) {
            double dx = (pix - (double)jx[k]) + sv0;
            double dy = (piy - (double)jy[k]) + sv1;
            double dz = (piz - (double)jz[k]) + sv2;
            double d2 = dx*dx + dy*dy + dz*dz;
            d2v[k] = (float)d2;
#pragma unroll
            for (int c = 0; c < NCUT; ++c) mv[c][k] = (d2 < cut2[c]) ? 1.0f : 0.0f;
        }

        const unsigned t0 = ((unsigned)s * (unsigned)n + i) * (unsigned)n + j0 + Pc;
        __builtin_nontemporal_store(d2v, (f32x4*)(out + t0));
#pragma unroll
        for (int c = 0; c < NCUT; ++c)
            __builtin_nontemporal_store(mv[c], (f32x4*)(out + (unsigned)(c + 1) * P + t0));
    } else {
        // ---------------- in-cell triangular region ----------------
        const unsigned p0 = ((blockIdx.y * 256u) + (unsigned)tid) << 2;
        if (p0 >= Pc) return;

        const long long tn = 2LL * n - 1;
        f32x4 d2v;
        f32x4 mv[NCUT];
#pragma unroll
        for (int k = 0; k < 4; ++k) {
            long long p = (long long)p0 + k;
            double D = (double)(tn * tn) - 8.0 * (double)p;
            long long i = (long long)(((double)tn - sqrt(D)) * 0.5);
            if (i < 0) i = 0;
            if (i > n - 2) i = n - 2;
            while ((i + 1) * (tn - (i + 1)) / 2 <= p) ++i;   // A(i+1) <= p
            while (i * (tn - i) / 2 > p) --i;                // A(i)   >  p
            long long j = p - i * (tn - i) / 2 + i + 1;

            double dx = (double)pos[3*i+0] - (double)pos[3*j+0];
            double dy = (double)pos[3*i+1] - (double)pos[3*j+1];
            double dz = (double)pos[3*i+2] - (double)pos[3*j+2];
            double d2 = dx*dx + dy*dy + dz*dz;
            d2v[k] = (float)d2;
#pragma unroll
            for (int c = 0; c < NCUT; ++c) mv[c][k] = (d2 < cut2[c]) ? 1.0f : 0.0f;
        }

        __builtin_nontemporal_store(d2v, (f32x4*)(out + p0));
#pragma unroll
        for (int c = 0; c < NCUT; ++c)
            __builtin_nontemporal_store(mv[c], (f32x4*)(out + (unsigned)(c + 1) * P + p0));
    }
}

// Generic scalar fallback (any n, any ncut) — unused at n=1000.
__global__ void __launch_bounds__(256) nbr_scalar(
    const float* __restrict__ pos,
    const float* __restrict__ cell,
    const float* __restrict__ shifts,
    const float* __restrict__ cutoffs,
    int ncut, int n,
    float* __restrict__ out, long long P, long long Pc)
{
    long long p = (long long)blockIdx.x * 256 + threadIdx.x;
    if (p >= P) return;

    double d2;
    if (p >= Pc) {
        long long q = p - Pc;
        unsigned long long nn = (unsigned long long)n * n;
        unsigned s = (unsigned)(q / nn);
        unsigned long long r = q - (unsigned long long)s * nn;
        unsigned i = (unsigned)(r / n);
        unsigned j = (unsigned)(r - (unsigned long long)i * n);
        double s0 = (double)shifts[3*s+0], s1 = (double)shifts[3*s+1], s2 = (double)shifts[3*s+2];
        double sv0 = s0*(double)cell[0] + s1*(double)cell[3] + s2*(double)cell[6];
        double sv1 = s0*(double)cell[1] + s1*(double)cell[4] + s2*(double)cell[7];
        double sv2 = s0*(double)cell[2] + s1*(double)cell[5] + s2*(double)cell[8];
        double dx = ((double)pos[3*i+0] - (double)pos[3*j+0]) + sv0;
        double dy = ((double)pos[3*i+1] - (double)pos[3*j+1]) + sv1;
        double dz = ((double)pos[3*i+2] - (double)pos[3*j+2]) + sv2;
        d2 = dx*dx + dy*dy + dz*dz;
    } else {
        long long tn = 2LL * n - 1;
        double D = (double)(tn * tn) - 8.0 * (double)p;
        long long i = (long long)(((double)tn - sqrt(D)) * 0.5);
        if (i < 0) i = 0;
        if (i > n - 2) i = n - 2;
        while ((i + 1) * (tn - (i + 1)) / 2 <= p) ++i;
        while (i * (tn - i) / 2 > p) --i;
        long long j = p - i * (tn - i) / 2 + i + 1;
        double dx = (double)pos[3*i+0] - (double)pos[3*j+0];
        double dy = (double)pos[3*i+1] - (double)pos[3*j+1];
        double dz = (double)pos[3*i+2] - (double)pos[3*j+2];
        d2 = dx*dx + dy*dy + dz*dz;
    }
    out[p] = (float)d2;
    for (int c = 0; c < ncut; ++c) {
        double cv = (double)cutoffs[c];
        out[(long long)(c + 1) * P + p] = (d2 < cv * cv) ? 1.0f : 0.0f;
    }
}

extern "C" void kernel_launch(void* const* d_in, const int* in_sizes, int n_in,
                              void* d_out, int out_size, void* d_ws, size_t ws_size,
                              hipStream_t stream)
{
    const float* pos     = (const float*)d_in[0];
    const float* cell    = (const float*)d_in[1];
    const float* shifts  = (const float*)d_in[2];
    const float* cutoffs = (const float*)d_in[3];
    int n    = in_sizes[0] / 3;   // 1000
    int S    = in_sizes[2] / 3;   // 13
    int ncut = in_sizes[3];       // 2

    long long Pc = (long long)n * (n - 1) / 2;          // 499500
    long long P  = Pc + (long long)S * n * n;           // 13499500
    float* out = (float*)d_out;

    // fast path: n%4==0 (alignment), Pc fits in n blocks of 1024 elems
    // (n<=2049), 32-bit offsets (3P<2^31), templated ncut
    bool fast = ((n & 3) == 0) && (n <= 2049) && (ncut >= 1) && (ncut <= 4) &&
                (3 * P < (1LL << 31));
    if (fast) {
        dim3 grid(1, n, S + 1);
        unsigned uP = (unsigned)P, uPc = (unsigned)Pc;
        switch (ncut) {
        case 1: nbr_fast<1><<<grid, 256, 0, stream>>>(pos, cell, shifts, cutoffs, n, S, out, uP, uPc); break;
        case 2: nbr_fast<2><<<grid, 256, 0, stream>>>(pos, cell, shifts, cutoffs, n, S, out, uP, uPc); break;
        case 3: nbr_fast<3><<<grid, 256, 0, stream>>>(pos, cell, shifts, cutoffs, n, S, out, uP, uPc); break;
        default: nbr_fast<4><<<grid, 256, 0, stream>>>(pos, cell, shifts, cutoffs, n, S, out, uP, uPc); break;
        }
    } else {
        int blocks = (int)((P + 255) / 256);
        nbr_scalar<<<blocks, 256, 0, stream>>>(pos, cell, shifts, cutoffs,
                                               ncut, n, out, P, Pc);
    }
}

// Round 5
// 170.917 us; speedup vs baseline: 1.0747x; 1.0747x over previous
//
#include <hip/hip_runtime.h>
#include <math.h>

// PBC neighbor-list distances + per-cutoff masks, store-bandwidth-bound.
//
// Output layout (float32): [ d2[P] | mask0[P] | mask1[P] ... ]
//   P  = Pc + S*n*n,  Pc = n*(n-1)/2
//   p < Pc               : in-cell triu pair, row-major (i<j)
//   p = Pc + s*n*n+i*n+j : shifted-image pair (s,i,j)
// Masks written as float 0.0/1.0.
//
// Fast path (n%4==0, n<=2049, ncut<=4): grid (1, n, S+1).
//   z<S : shifted region. blockIdx.y=i, blockIdx.z=s are wave-uniform ->
//         shifts/cell/cutoffs/pos[i] become scalar loads; the f64 shift
//         matmul is computed once per wave, not per lane. Each thread owns
//         4 consecutive j (aligned float4 pos load + 3 float4 stores).
//   z==S: triangular region, 4 elements/thread, per-element (i,j) decode.
// All store offsets fit in 32 bits (3P < 2^31 at this size).
//
// Regular (cached) stores, NOT nontemporal: R4 A/B showed NT is neutral-to-
// worse; best measured round (R2) used normal stores.
//
// Distance math in f64 to match the numpy-f64 validator exactly at the
// mask boundary (d2 < cutoff^2): ~2-3 expected boundary flips across 13.5M
// pairs if done in f32, and one flip fails the mask threshold. f64 VALU
// cost is ~6 us; the kernel is store-bound, so this is nearly free.

typedef float f32x4 __attribute__((ext_vector_type(4)));

template <int NCUT>
__global__ void __launch_bounds__(256) nbr_fast(
    const float* __restrict__ pos,
    const float* __restrict__ cell,
    const float* __restrict__ shifts,
    const float* __restrict__ cutoffs,
    int n, int S,
    float* __restrict__ out, unsigned P, unsigned Pc)
{
    const int tid = threadIdx.x;
    const int s   = blockIdx.z;

    double cut2[NCUT];
#pragma unroll
    for (int c = 0; c < NCUT; ++c) {
        double cv = (double)cutoffs[c];
        cut2[c] = cv * cv;
    }

    if (s < S) {
        // ---------------- shifted-image region ----------------
        const unsigned j0 = (unsigned)tid << 2;
        if (j0 >= (unsigned)n) return;
        const unsigned i = blockIdx.y;

        // wave-uniform setup (scalar loads + once-per-wave f64)
        double s0 = (double)shifts[3*s+0], s1 = (double)shifts[3*s+1], s2 = (double)shifts[3*s+2];
        double sv0 = s0 * (double)cell[0] + s1 * (double)cell[3] + s2 * (double)cell[6];
        double sv1 = s0 * (double)cell[1] + s1 * (double)cell[4] + s2 * (double)cell[7];
        double sv2 = s0 * (double)cell[2] + s1 * (double)cell[5] + s2 * (double)cell[8];
        double pix = (double)pos[3*i+0];
        double piy = (double)pos[3*i+1];
        double piz = (double)pos[3*i+2];

        // 4 consecutive atoms j0..j0+3 = 12 floats, 16B-aligned (j0%4==0)
        const float4* pj = (const float4*)(pos + 3 * j0);
        float4 a = pj[0], b = pj[1], c4 = pj[2];
        float jx[4] = {a.x, a.w, b.z, c4.y};
        float jy[4] = {a.y, b.x, b.w, c4.z};
        float jz[4] = {a.z, b.y, c4.x, c4.w};

        f32x4 d2v;
        f32x4 mv[NCUT];
#pragma unroll
        for (int k = 0; k < 4; ++k) {
            double dx = (pix - (double)jx[k]) + sv0;
            double dy = (piy - (double)jy[k]) + sv1;
            double dz = (piz - (double)jz[k]) + sv2;
            double d2 = dx*dx + dy*dy + dz*dz;
            d2v[k] = (float)d2;
#pragma unroll
            for (int c = 0; c < NCUT; ++c) mv[c][k] = (d2 < cut2[c]) ? 1.0f : 0.0f;
        }

        const unsigned t0 = ((unsigned)s * (unsigned)n + i) * (unsigned)n + j0 + Pc;
        *(f32x4*)(out + t0) = d2v;
#pragma unroll
        for (int c = 0; c < NCUT; ++c)
            *(f32x4*)(out + (unsigned)(c + 1) * P + t0) = mv[c];
    } else {
        // ---------------- in-cell triangular region ----------------
        const unsigned p0 = ((blockIdx.y * 256u) + (unsigned)tid) << 2;
        if (p0 >= Pc) return;

        const long long tn = 2LL * n - 1;
        f32x4 d2v;
        f32x4 mv[NCUT];
#pragma unroll
        for (int k = 0; k < 4; ++k) {
            long long p = (long long)p0 + k;
            double D = (double)(tn * tn) - 8.0 * (double)p;
            long long i = (long long)(((double)tn - sqrt(D)) * 0.5);
            if (i < 0) i = 0;
            if (i > n - 2) i = n - 2;
            while ((i + 1) * (tn - (i + 1)) / 2 <= p) ++i;   // A(i+1) <= p
            while (i * (tn - i) / 2 > p) --i;                // A(i)   >  p
            long long j = p - i * (tn - i) / 2 + i + 1;

            double dx = (double)pos[3*i+0] - (double)pos[3*j+0];
            double dy = (double)pos[3*i+1] - (double)pos[3*j+1];
            double dz = (double)pos[3*i+2] - (double)pos[3*j+2];
            double d2 = dx*dx + dy*dy + dz*dz;
            d2v[k] = (float)d2;
#pragma unroll
            for (int c = 0; c < NCUT; ++c) mv[c][k] = (d2 < cut2[c]) ? 1.0f : 0.0f;
        }

        *(f32x4*)(out + p0) = d2v;
#pragma unroll
        for (int c = 0; c < NCUT; ++c)
            *(f32x4*)(out + (unsigned)(c + 1) * P + p0) = mv[c];
    }
}

// Generic scalar fallback (any n, any ncut) — unused at n=1000.
__global__ void __launch_bounds__(256) nbr_scalar(
    const float* __restrict__ pos,
    const float* __restrict__ cell,
    const float* __restrict__ shifts,
    const float* __restrict__ cutoffs,
    int ncut, int n,
    float* __restrict__ out, long long P, long long Pc)
{
    long long p = (long long)blockIdx.x * 256 + threadIdx.x;
    if (p >= P) return;

    double d2;
    if (p >= Pc) {
        long long q = p - Pc;
        unsigned long long nn = (unsigned long long)n * n;
        unsigned s = (unsigned)(q / nn);
        unsigned long long r = q - (unsigned long long)s * nn;
        unsigned i = (unsigned)(r / n);
        unsigned j = (unsigned)(r - (unsigned long long)i * n);
        double s0 = (double)shifts[3*s+0], s1 = (double)shifts[3*s+1], s2 = (double)shifts[3*s+2];
        double sv0 = s0*(double)cell[0] + s1*(double)cell[3] + s2*(double)cell[6];
        double sv1 = s0*(double)cell[1] + s1*(double)cell[4] + s2*(double)cell[7];
        double sv2 = s0*(double)cell[2] + s1*(double)cell[5] + s2*(double)cell[8];
        double dx = ((double)pos[3*i+0] - (double)pos[3*j+0]) + sv0;
        double dy = ((double)pos[3*i+1] - (double)pos[3*j+1]) + sv1;
        double dz = ((double)pos[3*i+2] - (double)pos[3*j+2]) + sv2;
        d2 = dx*dx + dy*dy + dz*dz;
    } else {
        long long tn = 2LL * n - 1;
        double D = (double)(tn * tn) - 8.0 * (double)p;
        long long i = (long long)(((double)tn - sqrt(D)) * 0.5);
        if (i < 0) i = 0;
        if (i > n - 2) i = n - 2;
        while ((i + 1) * (tn - (i + 1)) / 2 <= p) ++i;
        while (i * (tn - i) / 2 > p) --i;
        long long j = p - i * (tn - i) / 2 + i + 1;
        double dx = (double)pos[3*i+0] - (double)pos[3*j+0];
        double dy = (double)pos[3*i+1] - (double)pos[3*j+1];
        double dz = (double)pos[3*i+2] - (double)pos[3*j+2];
        d2 = dx*dx + dy*dy + dz*dz;
    }
    out[p] = (float)d2;
    for (int c = 0; c < ncut; ++c) {
        double cv = (double)cutoffs[c];
        out[(long long)(c + 1) * P + p] = (d2 < cv * cv) ? 1.0f : 0.0f;
    }
}

extern "C" void kernel_launch(void* const* d_in, const int* in_sizes, int n_in,
                              void* d_out, int out_size, void* d_ws, size_t ws_size,
                              hipStream_t stream)
{
    const float* pos     = (const float*)d_in[0];
    const float* cell    = (const float*)d_in[1];
    const float* shifts  = (const float*)d_in[2];
    const float* cutoffs = (const float*)d_in[3];
    int n    = in_sizes[0] / 3;   // 1000
    int S    = in_sizes[2] / 3;   // 13
    int ncut = in_sizes[3];       // 2

    long long Pc = (long long)n * (n - 1) / 2;          // 499500
    long long P  = Pc + (long long)S * n * n;           // 13499500
    float* out = (float*)d_out;

    bool fast = ((n & 3) == 0) && (n <= 2049) && (ncut >= 1) && (ncut <= 4) &&
                (3 * P < (1LL << 31));
    if (fast) {
        dim3 grid(1, n, S + 1);
        unsigned uP = (unsigned)P, uPc = (unsigned)Pc;
        switch (ncut) {
        case 1: nbr_fast<1><<<grid, 256, 0, stream>>>(pos, cell, shifts, cutoffs, n, S, out, uP, uPc); break;
        case 2: nbr_fast<2><<<grid, 256, 0, stream>>>(pos, cell, shifts, cutoffs, n, S, out, uP, uPc); break;
        case 3: nbr_fast<3><<<grid, 256, 0, stream>>>(pos, cell, shifts, cutoffs, n, S, out, uP, uPc); break;
        default: nbr_fast<4><<<grid, 256, 0, stream>>>(pos, cell, shifts, cutoffs, n, S, out, uP, uPc); break;
        }
    } else {
        int blocks = (int)((P + 255) / 256);
        nbr_scalar<<<blocks, 256, 0, stream>>>(pos, cell, shifts, cutoffs,
                                               ncut, n, out, P, Pc);
    }
}